// Round 1
// baseline (3368.039 us; speedup 1.0000x reference)
//
#include <hip/hip_runtime.h>

#define N_NODES  100000
#define N_EDGES  1600000
#define N_GRAPHS 128
#define D        108
#define IN_DIM   146

#define SCAN_TILE 1024
#define NB1 ((N_NODES + SCAN_TILE - 1) / SCAN_TILE)   // 98

// ---------------- degree histogram ----------------
__global__ void k_hist(const int* __restrict__ dst, int* __restrict__ deg) {
  int e = blockIdx.x * 256 + threadIdx.x;
  if (e < N_EDGES) atomicAdd(&deg[dst[e]], 1);
}

// ---------------- scan (exclusive prefix sum of deg -> offsets) ----------------
__global__ void k_scan1(const int* __restrict__ deg, int* __restrict__ incl,
                        int* __restrict__ blksum) {
  __shared__ int sh[256];
  int t = threadIdx.x;
  int base = blockIdx.x * SCAN_TILE + t * 4;
  int x[4]; int s = 0;
#pragma unroll
  for (int j = 0; j < 4; j++) {
    int i = base + j;
    x[j] = (i < N_NODES) ? deg[i] : 0;
    s += x[j];
  }
  sh[t] = s; __syncthreads();
  for (int off = 1; off < 256; off <<= 1) {
    int v = (t >= off) ? sh[t - off] : 0;
    __syncthreads();
    sh[t] += v;
    __syncthreads();
  }
  int run = (t > 0) ? sh[t - 1] : 0;
#pragma unroll
  for (int j = 0; j < 4; j++) {
    run += x[j];
    int i = base + j;
    if (i < N_NODES) incl[i] = run;
  }
  if (t == 255) blksum[blockIdx.x] = sh[255];
}

__global__ void k_scan2(const int* __restrict__ blksum, int* __restrict__ blkoff) {
  if (threadIdx.x == 0) {
    int run = 0;
    for (int i = 0; i < NB1; i++) { blkoff[i] = run; run += blksum[i]; }
  }
}

__global__ void k_scan3(const int* __restrict__ incl, const int* __restrict__ deg,
                        const int* __restrict__ blkoff, int* __restrict__ offsets,
                        int* __restrict__ cursor) {
  int i = blockIdx.x * 256 + threadIdx.x;
  if (i < N_NODES) {
    int v = incl[i] - deg[i] + blkoff[i >> 10];
    offsets[i] = v;
    cursor[i]  = v;
  }
  if (i == 0) offsets[N_NODES] = N_EDGES;
}

// ---------------- CSR scatter ----------------
__global__ void k_scatter(const int* __restrict__ src, const int* __restrict__ dst,
                          int* __restrict__ cursor, int* __restrict__ esrc) {
  int e = blockIdx.x * 256 + threadIdx.x;
  if (e < N_EDGES) {
    int p = atomicAdd(&cursor[dst[e]], 1);
    esrc[p] = src[e];
  }
}

// ---------------- fp32 GEMM: out[N,108] = act( sum_p Ap[N,K] @ Wp[108,K]^T + bias ) ----
// block: 256 threads, tile 128 rows x 108 cols, per-thread 8x7 register tile
#define BM 128
#define BK 16
__global__ __launch_bounds__(256)
void k_gemm(const float* __restrict__ A1, int lda1,
            const float* __restrict__ W1, int ldw1,
            const float* __restrict__ A2, int lda2,
            const float* __restrict__ W2, int ldw2,
            int K, int nparts,
            const float* __restrict__ bias, float* __restrict__ out, int do_relu) {
  __shared__ float As[BM][BK + 1];
  __shared__ float Ws[BK][112];
  int t = threadIdx.x;
  int cg = t & 15;   // cols 7*cg .. 7*cg+6
  int rg = t >> 4;   // rows 8*rg .. 8*rg+7
  int row0 = blockIdx.x * BM;

  float acc[8][7];
#pragma unroll
  for (int i = 0; i < 8; i++)
#pragma unroll
    for (int j = 0; j < 7; j++) acc[i][j] = 0.f;

  for (int p = 0; p < nparts; p++) {
    const float* A = p ? A2 : A1; int lda = p ? lda2 : lda1;
    const float* W = p ? W2 : W1; int ldw = p ? ldw2 : ldw1;
    for (int kc = 0; kc < K; kc += BK) {
      __syncthreads();
      // stage A tile: thread -> row t>>1, 8 consecutive k
      {
        int r = t >> 1;
        int kk0 = (t & 1) * 8;
        int gr = row0 + r;
#pragma unroll
        for (int j = 0; j < 8; j++) {
          int k = kc + kk0 + j;
          As[r][kk0 + j] = (gr < N_NODES && k < K) ? A[(size_t)gr * lda + k] : 0.f;
        }
      }
      // stage W tile transposed: Ws[kk][c] = W[c][kc+kk]
      {
#pragma unroll
        for (int j = 0; j < 7; j++) {
          int idx = t * 7 + j;          // 0..1791 = 112*16
          int kk = idx & 15;
          int c  = idx >> 4;
          int k  = kc + kk;
          Ws[kk][c] = (c < D && k < K) ? W[(size_t)c * ldw + k] : 0.f;
        }
      }
      __syncthreads();
#pragma unroll
      for (int kk = 0; kk < BK; kk++) {
        float a[8], w[7];
#pragma unroll
        for (int i = 0; i < 8; i++) a[i] = As[rg * 8 + i][kk];
#pragma unroll
        for (int j = 0; j < 7; j++) w[j] = Ws[kk][cg * 7 + j];
#pragma unroll
        for (int i = 0; i < 8; i++)
#pragma unroll
          for (int j = 0; j < 7; j++) acc[i][j] += a[i] * w[j];
      }
    }
  }
  // epilogue
#pragma unroll
  for (int i = 0; i < 8; i++) {
    int r = row0 + rg * 8 + i;
    if (r >= N_NODES) continue;
#pragma unroll
    for (int j = 0; j < 7; j++) {
      int c = cg * 7 + j;
      if (c >= D) continue;
      float v = acc[i][j] + bias[c];
      if (do_relu) v = fmaxf(v, 0.f);
      out[(size_t)r * D + c] = v;
    }
  }
}

// ---------------- pull aggregation: agg[v] = mean over in-edges of pooled[src] ----
__global__ __launch_bounds__(256)
void k_aggregate(const float* __restrict__ pooled, const int* __restrict__ offsets,
                 const int* __restrict__ esrc, float* __restrict__ agg) {
  int t = threadIdx.x;
  int sub = t >> 7;
  int d = t & 127;
  int v = blockIdx.x * 2 + sub;
  if (v >= N_NODES || d >= D) return;
  int s0 = offsets[v], s1 = offsets[v + 1];
  float acc = 0.f;
  for (int e = s0; e < s1; e++) {
    int s = esrc[e];
    acc += pooled[(size_t)s * D + d];
  }
  int dg = s1 - s0; if (dg < 1) dg = 1;
  agg[(size_t)v * D + d] = acc / (float)dg;
}

// ---------------- L2-normalize + relu + snorm + residual (in place on h) ----------
__global__ __launch_bounds__(128)
void k_norm_res(const float* __restrict__ raw, const float* __restrict__ snorm,
                float* __restrict__ h) {
  int v = blockIdx.x;
  int t = threadIdx.x;
  __shared__ float red[2];
  float val = (t < D) ? raw[(size_t)v * D + t] : 0.f;
  float ss = val * val;
#pragma unroll
  for (int off = 32; off > 0; off >>= 1) ss += __shfl_down(ss, off, 64);
  if ((t & 63) == 0) red[t >> 6] = ss;
  __syncthreads();
  float norm = sqrtf(red[0] + red[1]);
  float denom = fmaxf(norm, 1e-12f);
  if (t < D) {
    float x = val / denom;
    x = fmaxf(x, 0.f) * snorm[v];
    h[(size_t)v * D + t] += x;
  }
}

// ---------------- per-graph mean (graph_ids sorted) ----------------
__global__ __launch_bounds__(128)
void k_graph_mean(const float* __restrict__ h, const int* __restrict__ gid,
                  float* __restrict__ hg) {
  int g = blockIdx.x;
  int t = threadIdx.x;
  // lower_bound(g), lower_bound(g+1)
  int lo = 0, hi = N_NODES;
  while (lo < hi) { int mid = (lo + hi) >> 1; if (gid[mid] < g) lo = mid + 1; else hi = mid; }
  int s = lo;
  lo = s; hi = N_NODES;
  while (lo < hi) { int mid = (lo + hi) >> 1; if (gid[mid] < g + 1) lo = mid + 1; else hi = mid; }
  int e = lo;
  float acc = 0.f;
  if (t < D) {
    for (int v = s; v < e; v++) acc += h[(size_t)v * D + t];
  }
  int c = e - s; if (c < 1) c = 1;
  if (t < D) hg[g * D + t] = acc / (float)c;
}

// ---------------- MLP readout ----------------
__global__ __launch_bounds__(64)
void k_readout(const float* __restrict__ hg,
               const float* __restrict__ Wr0, const float* __restrict__ br0,
               const float* __restrict__ Wr1, const float* __restrict__ br1,
               const float* __restrict__ Wr2, const float* __restrict__ br2,
               float* __restrict__ out) {
  int g = blockIdx.x;
  int t = threadIdx.x;
  __shared__ float x0[D];
  __shared__ float x1[54];
  __shared__ float x2[27];
  for (int i = t; i < D; i += 64) x0[i] = hg[g * D + i];
  __syncthreads();
  if (t < 54) {
    float v = br0[t];
    for (int k = 0; k < D; k++) v += x0[k] * Wr0[t * D + k];
    x1[t] = fmaxf(v, 0.f);
  }
  __syncthreads();
  if (t < 27) {
    float v = br1[t];
    for (int k = 0; k < 54; k++) v += x1[k] * Wr1[t * 54 + k];
    x2[t] = fmaxf(v, 0.f);
  }
  __syncthreads();
  if (t < 10) {
    float v = br2[t];
    for (int k = 0; k < 27; k++) v += x2[k] * Wr2[t * 27 + k];
    out[g * 10 + t] = v;
  }
}

extern "C" void kernel_launch(void* const* d_in, const int* in_sizes, int n_in,
                              void* d_out, int out_size, void* d_ws, size_t ws_size,
                              hipStream_t stream) {
  const float* nodes_feat = (const float*)d_in[0];
  const float* snorm_n    = (const float*)d_in[1];
  const int*   src        = (const int*)d_in[2];
  const int*   dst        = (const int*)d_in[3];
  const int*   gid        = (const int*)d_in[4];
  const float* W_emb      = (const float*)d_in[6];
  const float* b_emb      = (const float*)d_in[7];
  const float* W_pool     = (const float*)d_in[8];
  const float* b_pool     = (const float*)d_in[9];
  const float* W_node     = (const float*)d_in[10];
  const float* b_node     = (const float*)d_in[11];
  const float* W_r0       = (const float*)d_in[12];
  const float* b_r0       = (const float*)d_in[13];
  const float* W_r1       = (const float*)d_in[14];
  const float* b_r1       = (const float*)d_in[15];
  const float* W_r2       = (const float*)d_in[16];
  const float* b_r2       = (const float*)d_in[17];
  float* out = (float*)d_out;

  // workspace layout
  char* ws = (char*)d_ws;
  size_t off = 0;
  auto alloc = [&](size_t bytes) { size_t o = off; off = (off + bytes + 255) & ~(size_t)255; return o; };
  float* h     = (float*)(ws + alloc((size_t)N_NODES * D * 4));
  float* buf1  = (float*)(ws + alloc((size_t)N_NODES * D * 4));   // pooled, then raw
  float* buf2  = (float*)(ws + alloc((size_t)N_NODES * D * 4));   // agg
  int*   esrc  = (int*)(ws + alloc((size_t)N_EDGES * 4));
  int*   deg   = (int*)(ws + alloc((size_t)N_NODES * 4));
  int*   offs  = (int*)(ws + alloc((size_t)(N_NODES + 1) * 4));
  int*   curs  = (int*)(ws + alloc((size_t)N_NODES * 4));
  int*   incl  = (int*)(ws + alloc((size_t)N_NODES * 4));
  int*   blks  = (int*)(ws + alloc((size_t)NB1 * 4));
  int*   blko  = (int*)(ws + alloc((size_t)NB1 * 4));
  float* hg    = (float*)(ws + alloc((size_t)N_GRAPHS * D * 4));
  (void)ws_size; (void)n_in; (void)in_sizes; (void)out_size;

  hipMemsetAsync(deg, 0, (size_t)N_NODES * 4, stream);

  // CSR build
  k_hist<<<(N_EDGES + 255) / 256, 256, 0, stream>>>(dst, deg);
  k_scan1<<<NB1, 256, 0, stream>>>(deg, incl, blks);
  k_scan2<<<1, 64, 0, stream>>>(blks, blko);
  k_scan3<<<(N_NODES + 255) / 256, 256, 0, stream>>>(incl, deg, blko, offs, curs);
  k_scatter<<<(N_EDGES + 255) / 256, 256, 0, stream>>>(src, dst, curs, esrc);

  int gemm_grid = (N_NODES + BM - 1) / BM;

  // embedding: h = nodes_feat @ W_emb^T + b_emb
  k_gemm<<<gemm_grid, 256, 0, stream>>>(nodes_feat, IN_DIM, W_emb, IN_DIM,
                                        nullptr, 0, nullptr, 0,
                                        IN_DIM, 1, b_emb, h, 0);

  for (int l = 0; l < 4; l++) {
    const float* Wp = W_pool + (size_t)l * D * D;
    const float* bp = b_pool + (size_t)l * D;
    const float* Wn = W_node + (size_t)l * D * 2 * D;
    const float* bn = b_node + (size_t)l * D;
    // pooled = relu(h @ Wp^T + bp)
    k_gemm<<<gemm_grid, 256, 0, stream>>>(h, D, Wp, D,
                                          nullptr, 0, nullptr, 0,
                                          D, 1, bp, buf1, 1);
    // agg = mean_in(pooled)
    k_aggregate<<<(N_NODES + 1) / 2, 256, 0, stream>>>(buf1, offs, esrc, buf2);
    // raw = h @ Wn[:, :108]^T + agg @ Wn[:, 108:]^T + bn
    k_gemm<<<gemm_grid, 256, 0, stream>>>(h, D, Wn, 2 * D,
                                          buf2, D, Wn + D, 2 * D,
                                          D, 2, bn, buf1, 0);
    // h += relu(raw / ||raw||) * snorm
    k_norm_res<<<N_NODES, 128, 0, stream>>>(buf1, snorm_n, h);
  }

  k_graph_mean<<<N_GRAPHS, 128, 0, stream>>>(h, gid, hg);
  k_readout<<<N_GRAPHS, 64, 0, stream>>>(hg, W_r0, b_r0, W_r1, b_r1, W_r2, b_r2, out);
}

// Round 2
// 1545.279 us; speedup vs baseline: 2.1796x; 2.1796x over previous
//
#include <hip/hip_runtime.h>
#include <hip/hip_bf16.h>

#define N_NODES  100000
#define N_PAD    100096
#define N_EDGES  1600000
#define N_GRAPHS 128
#define D        108
#define IN_DIM   146
#define KP_H     128      // padded K for h/agg (multiple of 32)
#define KP_NF    160      // padded K for nodes_feat

#define SCAN_TILE 1024
#define NB1 ((N_NODES + SCAN_TILE - 1) / SCAN_TILE)   // 98

typedef __bf16 bf16x8 __attribute__((ext_vector_type(8)));
typedef float  f32x4  __attribute__((ext_vector_type(4)));

__device__ __forceinline__ unsigned short f2bf_bits(float v) {
  __hip_bfloat16 b = __float2bfloat16(v);
  return __builtin_bit_cast(unsigned short, b);
}
__device__ __forceinline__ float bf_bits2f(unsigned short u) {
  __hip_bfloat16 b = __builtin_bit_cast(__hip_bfloat16, u);
  return __bfloat162float(b);
}
__device__ __forceinline__ void splitf(float v, unsigned short& hi, unsigned short& lo) {
  hi = f2bf_bits(v);
  lo = f2bf_bits(v - bf_bits2f(hi));
}

// ---------------- degree histogram ----------------
__global__ void k_hist(const int* __restrict__ dst, int* __restrict__ deg) {
  int e = blockIdx.x * 256 + threadIdx.x;
  if (e < N_EDGES) atomicAdd(&deg[dst[e]], 1);
}

// ---------------- scan ----------------
__global__ void k_scan1(const int* __restrict__ deg, int* __restrict__ incl,
                        int* __restrict__ blksum) {
  __shared__ int sh[256];
  int t = threadIdx.x;
  int base = blockIdx.x * SCAN_TILE + t * 4;
  int x[4]; int s = 0;
#pragma unroll
  for (int j = 0; j < 4; j++) {
    int i = base + j;
    x[j] = (i < N_NODES) ? deg[i] : 0;
    s += x[j];
  }
  sh[t] = s; __syncthreads();
  for (int off = 1; off < 256; off <<= 1) {
    int v = (t >= off) ? sh[t - off] : 0;
    __syncthreads();
    sh[t] += v;
    __syncthreads();
  }
  int run = (t > 0) ? sh[t - 1] : 0;
#pragma unroll
  for (int j = 0; j < 4; j++) {
    run += x[j];
    int i = base + j;
    if (i < N_NODES) incl[i] = run;
  }
  if (t == 255) blksum[blockIdx.x] = sh[255];
}

__global__ void k_scan2(const int* __restrict__ blksum, int* __restrict__ blkoff) {
  if (threadIdx.x == 0) {
    int run = 0;
    for (int i = 0; i < NB1; i++) { blkoff[i] = run; run += blksum[i]; }
  }
}

__global__ void k_scan3(const int* __restrict__ incl, const int* __restrict__ deg,
                        const int* __restrict__ blkoff, int* __restrict__ offsets,
                        int* __restrict__ cursor) {
  int i = blockIdx.x * 256 + threadIdx.x;
  if (i < N_NODES) {
    int v = incl[i] - deg[i] + blkoff[i >> 10];
    offsets[i] = v;
    cursor[i]  = v;
  }
  if (i == 0) offsets[N_NODES] = N_EDGES;
}

__global__ void k_scatter(const int* __restrict__ src, const int* __restrict__ dst,
                          int* __restrict__ cursor, int* __restrict__ esrc) {
  int e = blockIdx.x * 256 + threadIdx.x;
  if (e < N_EDGES) {
    int p = atomicAdd(&cursor[dst[e]], 1);
    esrc[p] = src[e];
  }
}

// ---------------- split nodes_feat into padded bf16 hi/lo ----------------
__global__ void k_split_nf(const float* __restrict__ nf,
                           __hip_bfloat16* __restrict__ hi, __hip_bfloat16* __restrict__ lo) {
  size_t stride = (size_t)gridDim.x * blockDim.x;
  for (size_t i = (size_t)blockIdx.x * blockDim.x + threadIdx.x;
       i < (size_t)N_PAD * KP_NF; i += stride) {
    int row = (int)(i / KP_NF), k = (int)(i % KP_NF);
    float v = (row < N_NODES && k < IN_DIM) ? nf[(size_t)row * IN_DIM + k] : 0.f;
    unsigned short h, l; splitf(v, h, l);
    hi[i] = __builtin_bit_cast(__hip_bfloat16, h);
    lo[i] = __builtin_bit_cast(__hip_bfloat16, l);
  }
}

// ---------------- split + pad all weights into one packed pair ----------------
// layout: [0,17920) Wemb [112][160]; then 4x wpool [112][128]; 4x wnode1; 4x wnode2
#define WEMB_OFF   0
#define WPOOL_OFF  17920
#define WNODE1_OFF (17920 + 4*14336)
#define WNODE2_OFF (17920 + 8*14336)
#define W_TOTAL    (17920 + 12*14336)

__global__ void k_split_w(const float* __restrict__ W_emb, const float* __restrict__ W_pool,
                          const float* __restrict__ W_node,
                          __hip_bfloat16* __restrict__ hi, __hip_bfloat16* __restrict__ lo) {
  size_t stride = (size_t)gridDim.x * blockDim.x;
  for (size_t i = (size_t)blockIdx.x * blockDim.x + threadIdx.x; i < W_TOTAL; i += stride) {
    float v = 0.f;
    if (i < WPOOL_OFF) {
      int r = (int)(i / KP_NF), k = (int)(i % KP_NF);
      if (r < D && k < IN_DIM) v = W_emb[(size_t)r * IN_DIM + k];
    } else {
      size_t i2 = i - WPOOL_OFF;
      int seg = (int)(i2 / (4 * 14336));
      size_t r2 = i2 % (4 * 14336);
      int l = (int)(r2 / 14336);
      int n = (int)((r2 % 14336) / KP_H);
      int k = (int)(r2 % KP_H);
      if (n < D && k < D) {
        if (seg == 0)      v = W_pool[(size_t)l * D * D + (size_t)n * D + k];
        else if (seg == 1) v = W_node[(size_t)l * D * 2 * D + (size_t)n * 2 * D + k];
        else               v = W_node[(size_t)l * D * 2 * D + (size_t)n * 2 * D + D + k];
      }
    }
    unsigned short h, l2; splitf(v, h, l2);
    hi[i] = __builtin_bit_cast(__hip_bfloat16, h);
    lo[i] = __builtin_bit_cast(__hip_bfloat16, l2);
  }
}

// ---------------- zero pad rows/cols of h hi/lo ----------------
__global__ void k_padinit(__hip_bfloat16* __restrict__ hHi, __hip_bfloat16* __restrict__ hLo) {
  size_t stride = (size_t)gridDim.x * blockDim.x;
  __hip_bfloat16 z = __float2bfloat16(0.f);
  for (size_t i = (size_t)blockIdx.x * blockDim.x + threadIdx.x;
       i < (size_t)N_PAD * KP_H; i += stride) {
    int row = (int)(i >> 7), col = (int)(i & 127);
    if (col >= D || row >= N_NODES) { hHi[i] = z; hLo[i] = z; }
  }
}

// ---------------- MFMA split-bf16 GEMM ----------------
// out[m][n] = act( sum_parts A[m][:] . W[n][:] + bias[n] ), M=N_PAD rows, n<112 (store n<108)
// A, W given as bf16 hi/lo arrays, row-major, K padded to 32*ks. lda/ldw in bf16x8 units.
__global__ __launch_bounds__(256)
void k_mm(const __hip_bfloat16* __restrict__ A1h_, const __hip_bfloat16* __restrict__ A1l_, int lda1, int ks1,
          const __hip_bfloat16* __restrict__ W1h_, const __hip_bfloat16* __restrict__ W1l_, int ldw1,
          const __hip_bfloat16* __restrict__ A2h_, const __hip_bfloat16* __restrict__ A2l_, int lda2, int ks2,
          const __hip_bfloat16* __restrict__ W2h_, const __hip_bfloat16* __restrict__ W2l_, int ldw2,
          const float* __restrict__ bias,
          float* __restrict__ outF,
          __hip_bfloat16* __restrict__ outHi, __hip_bfloat16* __restrict__ outLo,
          int relu)
{
  const int t = threadIdx.x;
  const int lane = t & 63;
  const int wv = t >> 6;
  const int r15 = lane & 15;
  const int q = lane >> 4;
  const long m0 = (long)blockIdx.x * 128 + wv * 32;

  f32x4 acc[2][7];
#pragma unroll
  for (int i = 0; i < 2; i++)
#pragma unroll
    for (int j = 0; j < 7; j++) acc[i][j] = f32x4{0.f, 0.f, 0.f, 0.f};

  auto run = [&](const __hip_bfloat16* Ah_, const __hip_bfloat16* Al_, int lda, int ks,
                 const __hip_bfloat16* Wh_, const __hip_bfloat16* Wl_, int ldw) {
    const bf16x8* Ah = (const bf16x8*)Ah_;
    const bf16x8* Al = (const bf16x8*)Al_;
    const bf16x8* Wh = (const bf16x8*)Wh_;
    const bf16x8* Wl = (const bf16x8*)Wl_;
    size_t a0 = (size_t)(m0 + r15) * lda + q;
    size_t a1 = a0 + (size_t)16 * lda;
    size_t b0 = (size_t)r15 * ldw + q;
    for (int s = 0; s < ks; ++s) {
      bf16x8 ah0 = Ah[a0], al0 = Al[a0];
      bf16x8 ah1 = Ah[a1], al1 = Al[a1];
#pragma unroll
      for (int n = 0; n < 7; ++n) {
        size_t bi = b0 + (size_t)(n * 16) * ldw;
        bf16x8 bh = Wh[bi], bl = Wl[bi];
        acc[0][n] = __builtin_amdgcn_mfma_f32_16x16x32_bf16(ah0, bh, acc[0][n], 0, 0, 0);
        acc[0][n] = __builtin_amdgcn_mfma_f32_16x16x32_bf16(ah0, bl, acc[0][n], 0, 0, 0);
        acc[0][n] = __builtin_amdgcn_mfma_f32_16x16x32_bf16(al0, bh, acc[0][n], 0, 0, 0);
        acc[1][n] = __builtin_amdgcn_mfma_f32_16x16x32_bf16(ah1, bh, acc[1][n], 0, 0, 0);
        acc[1][n] = __builtin_amdgcn_mfma_f32_16x16x32_bf16(ah1, bl, acc[1][n], 0, 0, 0);
        acc[1][n] = __builtin_amdgcn_mfma_f32_16x16x32_bf16(al1, bh, acc[1][n], 0, 0, 0);
      }
      a0 += 4; a1 += 4; b0 += 4;
    }
  };
  run(A1h_, A1l_, lda1, ks1, W1h_, W1l_, ldw1);
  if (A2h_) run(A2h_, A2l_, lda2, ks2, W2h_, W2l_, ldw2);

#pragma unroll
  for (int ms = 0; ms < 2; ++ms) {
#pragma unroll
    for (int n = 0; n < 7; ++n) {
      int col = n * 16 + r15;
      if (col >= D) continue;
      float bv = bias[col];
#pragma unroll
      for (int r = 0; r < 4; ++r) {
        long row = m0 + ms * 16 + q * 4 + r;
        if (row >= N_NODES) continue;
        float v = acc[ms][n][r] + bv;
        if (relu) v = fmaxf(v, 0.f);
        if (outF) outF[(size_t)row * D + col] = v;
        if (outHi) {
          unsigned short h, l; splitf(v, h, l);
          outHi[(size_t)row * KP_H + col] = __builtin_bit_cast(__hip_bfloat16, h);
          outLo[(size_t)row * KP_H + col] = __builtin_bit_cast(__hip_bfloat16, l);
        }
      }
    }
  }
}

// ---------------- pull aggregation: one wave per node, float2 per lane ----------------
__global__ __launch_bounds__(256)
void k_aggregate(const float* __restrict__ pooled, const int* __restrict__ offsets,
                 const int* __restrict__ esrc,
                 unsigned int* __restrict__ aggHi, unsigned int* __restrict__ aggLo)
{
  int t = threadIdx.x;
  int lane = t & 63;
  int v = blockIdx.x * 4 + (t >> 6);
  if (v >= N_PAD) return;
  float ax = 0.f, ay = 0.f;
  if (v < N_NODES && lane < 54) {
    int s0 = offsets[v], s1 = offsets[v + 1];
    const float2* P = (const float2*)pooled;
    float ax0 = 0.f, ay0 = 0.f, ax1 = 0.f, ay1 = 0.f;
    int e = s0;
    for (; e + 1 < s1; e += 2) {
      int sa = esrc[e], sb = esrc[e + 1];
      float2 pa = P[(size_t)sa * 54 + lane];
      float2 pb = P[(size_t)sb * 54 + lane];
      ax0 += pa.x; ay0 += pa.y; ax1 += pb.x; ay1 += pb.y;
    }
    if (e < s1) {
      int sa = esrc[e];
      float2 pa = P[(size_t)sa * 54 + lane];
      ax0 += pa.x; ay0 += pa.y;
    }
    int dgi = s1 - s0; if (dgi < 1) dgi = 1;
    float dg = (float)dgi;
    ax = (ax0 + ax1) / dg;
    ay = (ay0 + ay1) / dg;
  }
  unsigned short hx, lx, hy, ly;
  splitf(ax, hx, lx); splitf(ay, hy, ly);
  aggHi[(size_t)v * 64 + lane] = (unsigned int)hx | ((unsigned int)hy << 16);
  aggLo[(size_t)v * 64 + lane] = (unsigned int)lx | ((unsigned int)ly << 16);
}

// ---------------- L2-normalize + relu + snorm + residual, h kept as hi/lo ----------
__global__ __launch_bounds__(128)
void k_norm_res(const float* __restrict__ raw, const float* __restrict__ snorm,
                __hip_bfloat16* __restrict__ hHi, __hip_bfloat16* __restrict__ hLo) {
  int v = blockIdx.x;
  int t = threadIdx.x;
  __shared__ float red[2];
  float val = (t < D) ? raw[(size_t)v * D + t] : 0.f;
  float ss = val * val;
#pragma unroll
  for (int off = 32; off > 0; off >>= 1) ss += __shfl_down(ss, off, 64);
  if ((t & 63) == 0) red[t >> 6] = ss;
  __syncthreads();
  float denom = fmaxf(sqrtf(red[0] + red[1]), 1e-12f);
  if (t < D) {
    size_t idx = (size_t)v * KP_H + t;
    float hv = __bfloat162float(hHi[idx]) + __bfloat162float(hLo[idx]);
    float x = fmaxf(val / denom, 0.f) * snorm[v];
    float nh = hv + x;
    unsigned short h, l; splitf(nh, h, l);
    hHi[idx] = __builtin_bit_cast(__hip_bfloat16, h);
    hLo[idx] = __builtin_bit_cast(__hip_bfloat16, l);
  }
}

// ---------------- per-graph mean ----------------
__global__ __launch_bounds__(512)
void k_graph_mean(const __hip_bfloat16* __restrict__ hHi, const __hip_bfloat16* __restrict__ hLo,
                  const int* __restrict__ gid, float* __restrict__ hg) {
  int g = blockIdx.x;
  int t = threadIdx.x;
  int c = t & 127, rp = t >> 7;
  __shared__ float part[4][D];
  int lo = 0, hi = N_NODES;
  while (lo < hi) { int m = (lo + hi) >> 1; if (gid[m] < g) lo = m + 1; else hi = m; }
  int s = lo;
  hi = N_NODES;
  while (lo < hi) { int m = (lo + hi) >> 1; if (gid[m] < g + 1) lo = m + 1; else hi = m; }
  int e = lo;
  if (c < D) {
    float acc = 0.f;
    for (int v = s + rp; v < e; v += 4) {
      size_t idx = (size_t)v * KP_H + c;
      acc += __bfloat162float(hHi[idx]) + __bfloat162float(hLo[idx]);
    }
    part[rp][c] = acc;
  }
  __syncthreads();
  if (t < D) {
    int cnt = e - s; if (cnt < 1) cnt = 1;
    hg[g * D + t] = (part[0][t] + part[1][t] + part[2][t] + part[3][t]) / (float)cnt;
  }
}

// ---------------- MLP readout ----------------
__global__ __launch_bounds__(64)
void k_readout(const float* __restrict__ hg,
               const float* __restrict__ Wr0, const float* __restrict__ br0,
               const float* __restrict__ Wr1, const float* __restrict__ br1,
               const float* __restrict__ Wr2, const float* __restrict__ br2,
               float* __restrict__ out) {
  int g = blockIdx.x;
  int t = threadIdx.x;
  __shared__ float x0[D];
  __shared__ float x1[54];
  __shared__ float x2[27];
  for (int i = t; i < D; i += 64) x0[i] = hg[g * D + i];
  __syncthreads();
  if (t < 54) {
    float v = br0[t];
    for (int k = 0; k < D; k++) v += x0[k] * Wr0[t * D + k];
    x1[t] = fmaxf(v, 0.f);
  }
  __syncthreads();
  if (t < 27) {
    float v = br1[t];
    for (int k = 0; k < 54; k++) v += x1[k] * Wr1[t * 54 + k];
    x2[t] = fmaxf(v, 0.f);
  }
  __syncthreads();
  if (t < 10) {
    float v = br2[t];
    for (int k = 0; k < 27; k++) v += x2[k] * Wr2[t * 27 + k];
    out[g * 10 + t] = v;
  }
}

extern "C" void kernel_launch(void* const* d_in, const int* in_sizes, int n_in,
                              void* d_out, int out_size, void* d_ws, size_t ws_size,
                              hipStream_t stream) {
  const float* nodes_feat = (const float*)d_in[0];
  const float* snorm_n    = (const float*)d_in[1];
  const int*   src        = (const int*)d_in[2];
  const int*   dst        = (const int*)d_in[3];
  const int*   gid        = (const int*)d_in[4];
  const float* W_emb      = (const float*)d_in[6];
  const float* b_emb      = (const float*)d_in[7];
  const float* W_pool     = (const float*)d_in[8];
  const float* b_pool     = (const float*)d_in[9];
  const float* W_node     = (const float*)d_in[10];
  const float* b_node     = (const float*)d_in[11];
  const float* W_r0       = (const float*)d_in[12];
  const float* b_r0       = (const float*)d_in[13];
  const float* W_r1       = (const float*)d_in[14];
  const float* b_r1       = (const float*)d_in[15];
  const float* W_r2       = (const float*)d_in[16];
  const float* b_r2       = (const float*)d_in[17];
  float* out = (float*)d_out;

  char* ws = (char*)d_ws;
  size_t off = 0;
  auto alloc = [&](size_t bytes) { size_t o = off; off = (off + bytes + 255) & ~(size_t)255; return o; };

  float* buf1 = (float*)(ws + alloc((size_t)N_NODES * D * 4));          // pooled / raw
  __hip_bfloat16* h_hi = (__hip_bfloat16*)(ws + alloc((size_t)N_PAD * KP_H * 2));
  __hip_bfloat16* h_lo = (__hip_bfloat16*)(ws + alloc((size_t)N_PAD * KP_H * 2));
  // nf (pair, [N_PAD][160]) aliased with agg (pair, [N_PAD][128]) — disjoint lifetimes
  char* nfagg = ws + alloc((size_t)N_PAD * KP_NF * 2 * 2);
  __hip_bfloat16* nf_hi = (__hip_bfloat16*)nfagg;
  __hip_bfloat16* nf_lo = (__hip_bfloat16*)(nfagg + (size_t)N_PAD * KP_NF * 2);
  __hip_bfloat16* agg_hi = (__hip_bfloat16*)nfagg;
  __hip_bfloat16* agg_lo = (__hip_bfloat16*)(nfagg + (size_t)N_PAD * KP_H * 2);
  int* esrc = (int*)(ws + alloc((size_t)N_EDGES * 4));
  int* deg  = (int*)(ws + alloc((size_t)N_NODES * 4));
  int* offs = (int*)(ws + alloc((size_t)(N_NODES + 1) * 4));
  int* curs = (int*)(ws + alloc((size_t)N_NODES * 4));
  int* incl = (int*)(ws + alloc((size_t)N_NODES * 4));
  int* blks = (int*)(ws + alloc((size_t)NB1 * 4));
  int* blko = (int*)(ws + alloc((size_t)NB1 * 4));
  __hip_bfloat16* wHi = (__hip_bfloat16*)(ws + alloc((size_t)W_TOTAL * 2));
  __hip_bfloat16* wLo = (__hip_bfloat16*)(ws + alloc((size_t)W_TOTAL * 2));
  float* hg = (float*)(ws + alloc((size_t)N_GRAPHS * D * 4));
  (void)ws_size; (void)n_in; (void)in_sizes; (void)out_size;

  hipMemsetAsync(deg, 0, (size_t)N_NODES * 4, stream);

  // CSR build
  k_hist<<<(N_EDGES + 255) / 256, 256, 0, stream>>>(dst, deg);
  k_scan1<<<NB1, 256, 0, stream>>>(deg, incl, blks);
  k_scan2<<<1, 64, 0, stream>>>(blks, blko);
  k_scan3<<<(N_NODES + 255) / 256, 256, 0, stream>>>(incl, deg, blko, offs, curs);
  k_scatter<<<(N_EDGES + 255) / 256, 256, 0, stream>>>(src, dst, curs, esrc);

  // splits + pad init
  k_split_w<<<(W_TOTAL + 255) / 256, 256, 0, stream>>>(W_emb, W_pool, W_node, wHi, wLo);
  k_split_nf<<<4096, 256, 0, stream>>>(nodes_feat, nf_hi, nf_lo);
  k_padinit<<<8192, 256, 0, stream>>>(h_hi, h_lo);

  const int GEMM_GRID = N_PAD / 128;  // 782

  // embedding: h = nodes_feat @ W_emb^T + b_emb  (write split only)
  k_mm<<<GEMM_GRID, 256, 0, stream>>>(nf_hi, nf_lo, KP_NF / 8, KP_NF / 32,
                                      wHi + WEMB_OFF, wLo + WEMB_OFF, KP_NF / 8,
                                      nullptr, nullptr, 0, 0, nullptr, nullptr, 0,
                                      b_emb, nullptr, h_hi, h_lo, 0);

  for (int l = 0; l < 4; l++) {
    const __hip_bfloat16* wpH = wHi + WPOOL_OFF + (size_t)l * 14336;
    const __hip_bfloat16* wpL = wLo + WPOOL_OFF + (size_t)l * 14336;
    const __hip_bfloat16* wn1H = wHi + WNODE1_OFF + (size_t)l * 14336;
    const __hip_bfloat16* wn1L = wLo + WNODE1_OFF + (size_t)l * 14336;
    const __hip_bfloat16* wn2H = wHi + WNODE2_OFF + (size_t)l * 14336;
    const __hip_bfloat16* wn2L = wLo + WNODE2_OFF + (size_t)l * 14336;
    const float* bp = b_pool + (size_t)l * D;
    const float* bn = b_node + (size_t)l * D;

    // pooled = relu(h @ Wp^T + bp)   (fp32 out)
    k_mm<<<GEMM_GRID, 256, 0, stream>>>(h_hi, h_lo, KP_H / 8, KP_H / 32,
                                        wpH, wpL, KP_H / 8,
                                        nullptr, nullptr, 0, 0, nullptr, nullptr, 0,
                                        bp, buf1, nullptr, nullptr, 1);
    // agg = mean_in(pooled)  (writes split hi/lo, covers pad rows with zeros)
    k_aggregate<<<N_PAD / 4, 256, 0, stream>>>(buf1, offs, esrc,
                                               (unsigned int*)agg_hi, (unsigned int*)agg_lo);
    // raw = h @ Wn1^T + agg @ Wn2^T + bn  (fp32 out)
    k_mm<<<GEMM_GRID, 256, 0, stream>>>(h_hi, h_lo, KP_H / 8, KP_H / 32,
                                        wn1H, wn1L, KP_H / 8,
                                        agg_hi, agg_lo, KP_H / 8, KP_H / 32,
                                        wn2H, wn2L, KP_H / 8,
                                        bn, buf1, nullptr, nullptr, 0);
    // h += relu(raw / ||raw||) * snorm
    k_norm_res<<<N_NODES, 128, 0, stream>>>(buf1, snorm_n, h_hi, h_lo);
  }

  k_graph_mean<<<N_GRAPHS, 512, 0, stream>>>(h_hi, h_lo, gid, hg);
  k_readout<<<N_GRAPHS, 64, 0, stream>>>(hg, W_r0, b_r0, W_r1, b_r1, W_r2, b_r2, out);
}